// Round 1
// baseline (2158.421 us; speedup 1.0000x reference)
//
#include <hip/hip_runtime.h>
#include <math.h>

#define NN 131072
#define EE 2097152
#define ET (EE + NN)
#define GG 512
#define BN_EPS 1e-5f

__device__ __forceinline__ float wave_max(float v) {
#pragma unroll
  for (int m = 32; m >= 1; m >>= 1) v = fmaxf(v, __shfl_xor(v, m, 64));
  return v;
}
__device__ __forceinline__ float wave_sum(float v) {
#pragma unroll
  for (int m = 32; m >= 1; m >>= 1) v += __shfl_xor(v, m, 64);
  return v;
}

// ---------------- CSR build ----------------
__global__ void k_hist(const int* __restrict__ ei, int* __restrict__ cnt) {
  int e = blockIdx.x * blockDim.x + threadIdx.x;
  if (e < EE) atomicAdd(&cnt[ei[EE + e]], 1);
}

__global__ void k_scan_a(const int* __restrict__ cnt, int* __restrict__ off_out,
                         int* __restrict__ bsum) {
  __shared__ int s[256];
  int i = blockIdx.x * 256 + threadIdx.x;
  int x = cnt[i] + 1;  // +1 self loop
  s[threadIdx.x] = x;
  __syncthreads();
#pragma unroll
  for (int o = 1; o < 256; o <<= 1) {
    int t = (threadIdx.x >= o) ? s[threadIdx.x - o] : 0;
    __syncthreads();
    s[threadIdx.x] += t;
    __syncthreads();
  }
  off_out[i] = s[threadIdx.x] - x;  // exclusive within block
  if (threadIdx.x == 255) bsum[blockIdx.x] = s[255];
}

__global__ void k_scan_b(int* __restrict__ bsum) {
  __shared__ int s[512];
  int t = threadIdx.x;
  int x = bsum[t];
  s[t] = x;
  __syncthreads();
#pragma unroll
  for (int o = 1; o < 512; o <<= 1) {
    int v = (t >= o) ? s[t - o] : 0;
    __syncthreads();
    s[t] += v;
    __syncthreads();
  }
  bsum[t] = s[t] - x;  // exclusive, in place
}

__global__ void k_scan_c(int* __restrict__ off_out, const int* __restrict__ bsum) {
  int i = blockIdx.x * 256 + threadIdx.x;
  off_out[i] += bsum[blockIdx.x];
  if (i == 0) off_out[NN] = ET;
}

__global__ void k_scatter(const int* __restrict__ ei, const float* __restrict__ ea,
                          const int* __restrict__ off, int* __restrict__ cur,
                          int* __restrict__ csrc, int* __restrict__ cdst,
                          float* __restrict__ cea) {
  int e = blockIdx.x * blockDim.x + threadIdx.x;
  if (e >= EE) return;
  int s = ei[e], d = ei[EE + e];
  int p = off[d] + atomicAdd(&cur[d], 1);
  csrc[p] = s;
  cdst[p] = d;
  cea[3 * p] = ea[3 * e];
  cea[3 * p + 1] = ea[3 * e + 1];
  cea[3 * p + 2] = ea[3 * e + 2];
}

// self-loop slot = last slot of each node; attr = mean of incoming real-edge attrs
__global__ void k_selfloop(const int* __restrict__ off, int* __restrict__ csrc,
                           int* __restrict__ cdst, float* __restrict__ cea) {
  int v = blockIdx.x * blockDim.x + threadIdx.x;
  if (v >= NN) return;
  int b = off[v];
  int d = off[v + 1] - b - 1;  // real in-degree
  float s0 = 0.f, s1 = 0.f, s2 = 0.f;
  for (int j = b; j < b + d; j++) {
    s0 += cea[3 * j];
    s1 += cea[3 * j + 1];
    s2 += cea[3 * j + 2];
  }
  float inv = 1.0f / (float)(d > 0 ? d : 1);
  int sl = b + d;
  csrc[sl] = v;
  cdst[sl] = v;
  cea[3 * sl] = s0 * inv;
  cea[3 * sl + 1] = s1 * inv;
  cea[3 * sl + 2] = s2 * inv;
}

// ---------------- per-layer kernels ----------------
// xl = x@wl+bl ; xr = x@wr+br   (K = in_dim, O = H*C)
template <int K, int O>
__global__ void k_lin(const float* __restrict__ x, const float* __restrict__ wl,
                      const float* __restrict__ bl, const float* __restrict__ wr,
                      const float* __restrict__ br, float* __restrict__ xl,
                      float* __restrict__ xr) {
  constexpr int NPB = 256 / O;  // nodes per block-iteration
  __shared__ float swl[K * O], swr[K * O], sx[NPB * K];
  for (int i = threadIdx.x; i < K * O; i += 256) {
    swl[i] = wl[i];
    swr[i] = wr[i];
  }
  int o = threadIdx.x % O;
  int ln = threadIdx.x / O;
  float blv = bl[o], brv = br[o];
  __syncthreads();
  for (int v0 = blockIdx.x * NPB; v0 < NN; v0 += gridDim.x * NPB) {
    __syncthreads();
    for (int i = threadIdx.x; i < NPB * K; i += 256) sx[i] = x[(size_t)v0 * K + i];
    __syncthreads();
    float al = blv, ar = brv;
#pragma unroll 8
    for (int k = 0; k < K; k++) {
      float xv = sx[ln * K + k];
      al += xv * swl[k * O + o];
      ar += xv * swr[k * O + o];
    }
    int v = v0 + ln;
    xl[(size_t)v * O + o] = al;
    xr[(size_t)v * O + o] = ar;
  }
}

// one wave per CSR slot: logit[e][h] = sum_c lrelu(xl[src]+xr[dst]+ee)*att
template <int HC>
__global__ void k_logit(const int* __restrict__ csrc, const int* __restrict__ cdst,
                        const float* __restrict__ cea, const float* __restrict__ xl,
                        const float* __restrict__ xr, const float* __restrict__ we,
                        const float* __restrict__ att, float* __restrict__ lg) {
  constexpr int CPL = HC / 64;
  int w = (blockIdx.x * blockDim.x + threadIdx.x) >> 6;
  if (w >= ET) return;
  int lane = threadIdx.x & 63;
  int s = csrc[w], d = cdst[w];
  float ea0 = cea[3 * w], ea1 = cea[3 * w + 1], ea2 = cea[3 * w + 2];
  float contrib = 0.0f;
#pragma unroll
  for (int i = 0; i < CPL; i++) {
    int hc = (lane >> 5) * (HC / 2) + (lane & 31) + i * 32;
    float m = xl[(size_t)s * HC + hc] + xr[(size_t)d * HC + hc] + ea0 * we[hc] +
              ea1 * we[HC + hc] + ea2 * we[2 * HC + hc];
    m = (m > 0.0f) ? m : 0.2f * m;
    contrib += m * att[hc];
  }
#pragma unroll
  for (int mk = 16; mk >= 1; mk >>= 1) contrib += __shfl_xor(contrib, mk, 64);
  if ((lane & 31) == 0) lg[2 * w + (lane >> 5)] = contrib;
}

// one wave per node: segment softmax over its slots + weighted sum of xl[src]
// + head mean + bias ; BN partial sums via LDS then few global atomics
template <int HC>
__global__ void k_accum(const int* __restrict__ off, const int* __restrict__ csrc,
                        const float* __restrict__ lg, const float* __restrict__ xl,
                        const float* __restrict__ bias, float* __restrict__ hout,
                        float* __restrict__ bnsum, float* __restrict__ bnss) {
  constexpr int C = HC / 2;
  constexpr int CPL = HC / 64;
  __shared__ float lsum[C], lss[C];
  if (threadIdx.x < C) {
    lsum[threadIdx.x] = 0.0f;
    lss[threadIdx.x] = 0.0f;
  }
  __syncthreads();
  int lane = threadIdx.x & 63;
  int wid = threadIdx.x >> 6;
  const float2* lg2 = (const float2*)lg;
  for (int v = blockIdx.x * 4 + wid; v < NN; v += gridDim.x * 4) {
    int b = off[v], e1 = off[v + 1];
    float mx0 = -1e30f, mx1 = -1e30f;
    for (int j = b + lane; j < e1; j += 64) {
      float2 l = lg2[j];
      mx0 = fmaxf(mx0, l.x);
      mx1 = fmaxf(mx1, l.y);
    }
    mx0 = wave_max(mx0);
    mx1 = wave_max(mx1);
    float s0 = 0.0f, s1 = 0.0f;
    for (int j = b + lane; j < e1; j += 64) {
      float2 l = lg2[j];
      s0 += __expf(l.x - mx0);
      s1 += __expf(l.y - mx1);
    }
    s0 = wave_sum(s0);
    s1 = wave_sum(s1);
    float inv = (lane >= 32) ? 1.0f / (s1 + 1e-16f) : 1.0f / (s0 + 1e-16f);
    float mym = (lane >= 32) ? mx1 : mx0;
    int hc0 = (lane >> 5) * C + (lane & 31);
    float acc0 = 0.0f, acc1 = 0.0f;
    for (int j = b; j < e1; j++) {
      int s = csrc[j];
      float2 l = lg2[j];
      float a = __expf(((lane >= 32) ? l.y : l.x) - mym) * inv;
      acc0 += a * xl[(size_t)s * HC + hc0];
      if (CPL == 2) acc1 += a * xl[(size_t)s * HC + hc0 + 32];
    }
    float o0 = __shfl_xor(acc0, 32, 64);
    float o1 = __shfl_xor(acc1, 32, 64);
    if (lane < 32) {
      int c = lane;  // hc0 == lane for head 0
      float v0 = 0.5f * (acc0 + o0) + bias[c];
      hout[(size_t)v * C + c] = v0;
      atomicAdd(&lsum[c], v0);
      atomicAdd(&lss[c], v0 * v0);
      if (CPL == 2) {
        int c1 = c + 32;
        float v1 = 0.5f * (acc1 + o1) + bias[c1];
        hout[(size_t)v * C + c1] = v1;
        atomicAdd(&lsum[c1], v1);
        atomicAdd(&lss[c1], v1 * v1);
      }
    }
  }
  __syncthreads();
  if (threadIdx.x < C) {
    atomicAdd(&bnsum[threadIdx.x], lsum[threadIdx.x]);
    atomicAdd(&bnss[threadIdx.x], lss[threadIdx.x]);
  }
}

template <int C>
__global__ void k_bn_elu(float* __restrict__ h, const float* __restrict__ bnsum,
                         const float* __restrict__ bnss, const float* __restrict__ g,
                         const float* __restrict__ be) {
  int i = blockIdx.x * blockDim.x + threadIdx.x;
  if (i >= NN * C) return;
  int c = i & (C - 1);
  float mu = bnsum[c] * (1.0f / NN);
  float var = bnss[c] * (1.0f / NN) - mu * mu;
  float y = (h[i] - mu) * rsqrtf(var + BN_EPS) * g[c] + be[c];
  h[i] = (y > 0.0f) ? y : (__expf(y) - 1.0f);
}

// ---------------- pooling + head ----------------
__global__ void k_gcount(const int* __restrict__ batch, int* __restrict__ gcount) {
  int v = blockIdx.x * blockDim.x + threadIdx.x;
  if (v < NN) atomicAdd(&gcount[batch[v]], 1);
}

__global__ void k_goff(const int* __restrict__ gcount, int* __restrict__ goff) {
  __shared__ int s[GG];
  int t = threadIdx.x;
  int x = gcount[t];
  s[t] = x;
  __syncthreads();
#pragma unroll
  for (int o = 1; o < GG; o <<= 1) {
    int v = (t >= o) ? s[t - o] : 0;
    __syncthreads();
    s[t] += v;
    __syncthreads();
  }
  goff[t] = s[t] - x;
}

__global__ void k_pool(const float* __restrict__ h2, const int* __restrict__ goff,
                       const int* __restrict__ gcount, float* __restrict__ pooled) {
  int g = blockIdx.x, c = threadIdx.x;  // 64 threads
  int s = goff[g], n = gcount[g];
  float acc = 0.0f;
  for (int i = 0; i < n; i++) acc += h2[(size_t)(s + i) * 64 + c];
  pooled[g * 64 + c] = acc / fmaxf((float)n, 1.0f);
}

__global__ void k_fc1(const float* __restrict__ pooled, const float* __restrict__ w,
                      const float* __restrict__ b, float* __restrict__ t1) {
  int i = blockIdx.x * blockDim.x + threadIdx.x;  // 16384
  int g = i >> 5, o = i & 31;
  float acc = b[o];
#pragma unroll 8
  for (int k = 0; k < 64; k++) acc += pooled[g * 64 + k] * w[k * 32 + o];
  t1[i] = acc;
}

__global__ void k_head(const float* __restrict__ t1, const float* __restrict__ g3,
                       const float* __restrict__ be3, const float* __restrict__ fc2w,
                       const float* __restrict__ fc2b, float* __restrict__ out) {
  __shared__ float ssum[32], ssq[32], smu[32], sinv[32];
  int t = threadIdx.x;  // 512 threads, one per graph
  if (t < 32) {
    ssum[t] = 0.0f;
    ssq[t] = 0.0f;
  }
  __syncthreads();
  float y[32];
#pragma unroll
  for (int o = 0; o < 32; o++) y[o] = t1[t * 32 + o];
#pragma unroll
  for (int o = 0; o < 32; o++) {
    atomicAdd(&ssum[o], y[o]);
    atomicAdd(&ssq[o], y[o] * y[o]);
  }
  __syncthreads();
  if (t < 32) {
    float mu = ssum[t] * (1.0f / GG);
    float var = ssq[t] * (1.0f / GG) - mu * mu;
    smu[t] = mu;
    sinv[t] = rsqrtf(var + BN_EPS);
  }
  __syncthreads();
  float acc = fc2b[0];
#pragma unroll
  for (int o = 0; o < 32; o++) {
    float yy = (y[o] - smu[o]) * sinv[o] * g3[o] + be3[o];
    yy = (yy > 0.0f) ? yy : (__expf(yy) - 1.0f);
    acc += yy * fc2w[o];
  }
  out[t] = 1.0f / (1.0f + __expf(-acc));
}

// ---------------- launch ----------------
extern "C" void kernel_launch(void* const* d_in, const int* in_sizes, int n_in,
                              void* d_out, int out_size, void* d_ws, size_t ws_size,
                              hipStream_t stream) {
  const float* x = (const float*)d_in[0];
  const float* ea = (const float*)d_in[1];
  const float* w1l = (const float*)d_in[2];
  const float* b1l = (const float*)d_in[3];
  const float* w1r = (const float*)d_in[4];
  const float* b1r = (const float*)d_in[5];
  const float* w1e = (const float*)d_in[6];
  const float* att1 = (const float*)d_in[7];
  const float* bias1 = (const float*)d_in[8];
  const float* g1 = (const float*)d_in[9];
  const float* be1 = (const float*)d_in[10];
  const float* w2l = (const float*)d_in[11];
  const float* b2l = (const float*)d_in[12];
  const float* w2r = (const float*)d_in[13];
  const float* b2r = (const float*)d_in[14];
  const float* w2e = (const float*)d_in[15];
  const float* att2 = (const float*)d_in[16];
  const float* bias2 = (const float*)d_in[17];
  const float* g2 = (const float*)d_in[18];
  const float* be2 = (const float*)d_in[19];
  const float* fc1w = (const float*)d_in[20];
  const float* fc1b = (const float*)d_in[21];
  const float* g3 = (const float*)d_in[22];
  const float* be3 = (const float*)d_in[23];
  const float* fc2w = (const float*)d_in[24];
  const float* fc2b = (const float*)d_in[25];
  const int* ei = (const int*)d_in[26];
  const int* batch = (const int*)d_in[27];
  float* out = (float*)d_out;

  char* w = (char*)d_ws;
  size_t off = 0;
  auto alloc = [&](size_t bytes) {
    size_t r = off;
    off += (bytes + 255) & ~(size_t)255;
    return r;
  };
  // zero-init region (one memset)
  int* cnt = (int*)(w + alloc(NN * 4));
  int* cur = (int*)(w + alloc(NN * 4));
  int* gcount = (int*)(w + alloc(GG * 4));
  float* bn1sum = (float*)(w + alloc(32 * 4));
  float* bn1ss = (float*)(w + alloc(32 * 4));
  float* bn2sum = (float*)(w + alloc(64 * 4));
  float* bn2ss = (float*)(w + alloc(64 * 4));
  size_t zero_bytes = off;
  // rest
  int* csr_off = (int*)(w + alloc((size_t)(NN + 1) * 4));
  int* bsum = (int*)(w + alloc(512 * 4));
  int* goff = (int*)(w + alloc((size_t)(GG + 1) * 4));
  int* csrc = (int*)(w + alloc((size_t)ET * 4));
  int* cdst = (int*)(w + alloc((size_t)ET * 4));
  float* cea = (float*)(w + alloc((size_t)ET * 12));
  float* xl = (float*)(w + alloc((size_t)NN * 128 * 4));
  float* xr = (float*)(w + alloc((size_t)NN * 128 * 4));
  float* lg = (float*)(w + alloc((size_t)ET * 8));
  float* h1 = (float*)(w + alloc((size_t)NN * 32 * 4));
  float* h2 = (float*)(w + alloc((size_t)NN * 64 * 4));
  float* pooled = (float*)(w + alloc((size_t)GG * 64 * 4));
  float* t1 = (float*)(w + alloc((size_t)GG * 32 * 4));
  (void)ws_size;
  (void)in_sizes;
  (void)n_in;
  (void)out_size;

  hipMemsetAsync(d_ws, 0, zero_bytes, stream);

  // CSR build
  k_hist<<<EE / 256, 256, 0, stream>>>(ei, cnt);
  k_scan_a<<<512, 256, 0, stream>>>(cnt, csr_off, bsum);
  k_scan_b<<<1, 512, 0, stream>>>(bsum);
  k_scan_c<<<512, 256, 0, stream>>>(csr_off, bsum);
  k_scatter<<<EE / 256, 256, 0, stream>>>(ei, ea, csr_off, cur, csrc, cdst, cea);
  k_selfloop<<<NN / 256, 256, 0, stream>>>(csr_off, csrc, cdst, cea);

  // layer 1 (HC=64, C=32)
  k_lin<64, 64><<<2048, 256, 0, stream>>>(x, w1l, b1l, w1r, b1r, xl, xr);
  k_logit<64><<<ET / 4, 256, 0, stream>>>(csrc, cdst, cea, xl, xr, w1e, att1, lg);
  k_accum<64><<<2048, 256, 0, stream>>>(csr_off, csrc, lg, xl, bias1, h1, bn1sum, bn1ss);
  k_bn_elu<32><<<NN * 32 / 256, 256, 0, stream>>>(h1, bn1sum, bn1ss, g1, be1);

  // layer 2 (HC=128, C=64)
  k_lin<32, 128><<<2048, 256, 0, stream>>>(h1, w2l, b2l, w2r, b2r, xl, xr);
  k_logit<128><<<ET / 4, 256, 0, stream>>>(csrc, cdst, cea, xl, xr, w2e, att2, lg);
  k_accum<128><<<2048, 256, 0, stream>>>(csr_off, csrc, lg, xl, bias2, h2, bn2sum, bn2ss);
  k_bn_elu<64><<<NN * 64 / 256, 256, 0, stream>>>(h2, bn2sum, bn2ss, g2, be2);

  // pooling + head
  k_gcount<<<NN / 256, 256, 0, stream>>>(batch, gcount);
  k_goff<<<1, GG, 0, stream>>>(gcount, goff);
  k_pool<<<GG, 64, 0, stream>>>(h2, goff, gcount, pooled);
  k_fc1<<<64, 256, 0, stream>>>(pooled, fc1w, fc1b, t1);
  k_head<<<1, GG, 0, stream>>>(t1, g3, be3, fc2w, fc2b, out);
}

// Round 2
// 1390.738 us; speedup vs baseline: 1.5520x; 1.5520x over previous
//
#include <hip/hip_runtime.h>
#include <math.h>

#define NN 131072
#define EE 2097152
#define ET (EE + NN)
#define GG 512
#define BN_EPS 1e-5f

// ---------------- CSR build ----------------
__global__ void k_hist(const int* __restrict__ ei, int* __restrict__ cnt) {
  int e = blockIdx.x * blockDim.x + threadIdx.x;
  if (e < EE) atomicAdd(&cnt[ei[EE + e]], 1);
}

__global__ void k_scan_a(const int* __restrict__ cnt, int* __restrict__ off_out,
                         int* __restrict__ bsum) {
  __shared__ int s[256];
  int i = blockIdx.x * 256 + threadIdx.x;
  int x = cnt[i] + 1;  // +1 self loop
  s[threadIdx.x] = x;
  __syncthreads();
#pragma unroll
  for (int o = 1; o < 256; o <<= 1) {
    int t = (threadIdx.x >= o) ? s[threadIdx.x - o] : 0;
    __syncthreads();
    s[threadIdx.x] += t;
    __syncthreads();
  }
  off_out[i] = s[threadIdx.x] - x;  // exclusive within block
  if (threadIdx.x == 255) bsum[blockIdx.x] = s[255];
}

__global__ void k_scan_b(int* __restrict__ bsum) {
  __shared__ int s[512];
  int t = threadIdx.x;
  int x = bsum[t];
  s[t] = x;
  __syncthreads();
#pragma unroll
  for (int o = 1; o < 512; o <<= 1) {
    int v = (t >= o) ? s[t - o] : 0;
    __syncthreads();
    s[t] += v;
    __syncthreads();
  }
  bsum[t] = s[t] - x;  // exclusive, in place
}

__global__ void k_scan_c(int* __restrict__ off_out, const int* __restrict__ bsum) {
  int i = blockIdx.x * 256 + threadIdx.x;
  off_out[i] += bsum[blockIdx.x];
  if (i == 0) off_out[NN] = ET;
}

__global__ void k_scatter(const int* __restrict__ ei, const float* __restrict__ ea,
                          const int* __restrict__ off, int* __restrict__ cur,
                          int* __restrict__ csrc, float* __restrict__ cea) {
  int e = blockIdx.x * blockDim.x + threadIdx.x;
  if (e >= EE) return;
  int s = ei[e], d = ei[EE + e];
  int p = off[d] + atomicAdd(&cur[d], 1);
  csrc[p] = s;
  cea[3 * p] = ea[3 * e];
  cea[3 * p + 1] = ea[3 * e + 1];
  cea[3 * p + 2] = ea[3 * e + 2];
}

// self-loop slot = last slot of each node; attr = mean of incoming real-edge attrs
__global__ void k_selfloop(const int* __restrict__ off, int* __restrict__ csrc,
                           float* __restrict__ cea) {
  int v = blockIdx.x * blockDim.x + threadIdx.x;
  if (v >= NN) return;
  int b = off[v];
  int d = off[v + 1] - b - 1;  // real in-degree
  float s0 = 0.f, s1 = 0.f, s2 = 0.f;
  for (int j = b; j < b + d; j++) {
    s0 += cea[3 * j];
    s1 += cea[3 * j + 1];
    s2 += cea[3 * j + 2];
  }
  float inv = 1.0f / (float)(d > 0 ? d : 1);
  int sl = b + d;
  csrc[sl] = v;
  cea[3 * sl] = s0 * inv;
  cea[3 * sl + 1] = s1 * inv;
  cea[3 * sl + 2] = s2 * inv;
}

// ---------------- node linear: xl = f(x)@wl+bl ; xr = f(x)@wr+br ----------------
// DO_BN: f = elu(bn(x)) using stats in bnsum/bnss (K must == C of previous layer)
template <int K, int O, bool DO_BN>
__global__ void k_lin(const float* __restrict__ x, const float* __restrict__ wl,
                      const float* __restrict__ bl, const float* __restrict__ wr,
                      const float* __restrict__ br, float* __restrict__ xl,
                      float* __restrict__ xr, const float* __restrict__ bnsum,
                      const float* __restrict__ bnss, const float* __restrict__ g,
                      const float* __restrict__ be) {
  constexpr int NPB = 256 / O;  // nodes per block-iteration
  __shared__ float swl[K * O], swr[K * O], sx[NPB * K];
  __shared__ float sscale[K], sshift[K];
  for (int i = threadIdx.x; i < K * O; i += 256) {
    swl[i] = wl[i];
    swr[i] = wr[i];
  }
  if (DO_BN && threadIdx.x < K) {
    int c = threadIdx.x;
    float mu = bnsum[c] * (1.0f / NN);
    float var = bnss[c] * (1.0f / NN) - mu * mu;
    float is = rsqrtf(var + BN_EPS) * g[c];
    sscale[c] = is;
    sshift[c] = be[c] - mu * is;
  }
  int o = threadIdx.x % O;
  int ln = threadIdx.x / O;
  float blv = bl[o], brv = br[o];
  __syncthreads();
  for (int v0 = blockIdx.x * NPB; v0 < NN; v0 += gridDim.x * NPB) {
    __syncthreads();
    for (int i = threadIdx.x; i < NPB * K; i += 256) {
      float xv = x[(size_t)v0 * K + i];
      if (DO_BN) {
        int c = i & (K - 1);
        xv = xv * sscale[c] + sshift[c];
        xv = (xv > 0.0f) ? xv : (__expf(xv) - 1.0f);
      }
      sx[i] = xv;
    }
    __syncthreads();
    float al = blv, ar = brv;
#pragma unroll 8
    for (int k = 0; k < K; k++) {
      float xv = sx[ln * K + k];
      al += xv * swl[k * O + o];
      ar += xv * swr[k * O + o];
    }
    int v = v0 + ln;
    xl[(size_t)v * O + o] = al;
    xr[(size_t)v * O + o] = ar;
  }
}

// ---------------- fused GATv2 edge phase: one wave per node, online softmax ----
// logit_e = sum_hc lrelu(xl[src]+xr[v]+ee)*att ; alpha=softmax over segment ;
// h[v] = mean_h( sum_e alpha*xl[src] ) + bias.  BN partials accumulated.
__device__ __forceinline__ float half_reduce(float v) {
#pragma unroll
  for (int m = 16; m >= 1; m >>= 1) v += __shfl_xor(v, m, 64);
  return v;  // sum within each 32-lane half (per head)
}

template <int HC>
__global__ void k_gat(const int* __restrict__ off, const int* __restrict__ csrc,
                      const float* __restrict__ cea, const float* __restrict__ xl,
                      const float* __restrict__ xr, const float* __restrict__ we,
                      const float* __restrict__ att, const float* __restrict__ bias,
                      float* __restrict__ hout, float* __restrict__ bnsum,
                      float* __restrict__ bnss) {
  constexpr int C = HC / 2;
  __shared__ float lsum[4][C], lsq[4][C];
  int lane = threadIdx.x & 63;
  int wid = threadIdx.x >> 6;
  int gw = blockIdx.x * 4 + wid;
  int nw = gridDim.x * 4;

  if (HC == 64) {
    const float w0 = we[lane], w1 = we[64 + lane], w2 = we[128 + lane];
    const float av = att[lane];
    float rs = 0.0f, rq = 0.0f;  // BN partials (lane<32 meaningful)
    for (int v = gw; v < NN; v += nw) {
      int b = off[v], e1 = off[v + 1];
      float xrv = xr[(size_t)v * 64 + lane];
      float mx = -1e30f, ssum = 0.0f, acc = 0.0f;
      int sA = csrc[b];
      float row = xl[(size_t)sA * 64 + lane];
      int sB = (b + 1 < e1) ? csrc[b + 1] : 0;
      for (int j = b; j < e1; j++) {
        float cur = row;
        float ea0 = cea[3 * j], ea1 = cea[3 * j + 1], ea2 = cea[3 * j + 2];
        if (j + 1 < e1) row = xl[(size_t)sB * 64 + lane];
        if (j + 2 < e1) sB = csrc[j + 2];
        float m = cur + xrv + ea0 * w0 + ea1 * w1 + ea2 * w2;
        m = (m > 0.0f) ? m : 0.2f * m;
        float l = half_reduce(m * av);  // per-head logit, uniform in half
        float nm = fmaxf(mx, l);
        float sc = __expf(mx - nm);
        float p = __expf(l - nm);
        ssum = ssum * sc + p;
        acc = acc * sc + p * cur;
        mx = nm;
      }
      float myout = acc * (1.0f / (ssum + 1e-16f));
      float other = __shfl_xor(myout, 32, 64);
      if (lane < 32) {
        float val = 0.5f * (myout + other) + bias[lane];
        hout[(size_t)v * 32 + lane] = val;
        rs += val;
        rq += val * val;
      }
    }
    if (lane < 32) {
      lsum[wid][lane] = rs;
      lsq[wid][lane] = rq;
    }
  } else {  // HC == 128, float2 units: lane holds channels 2*(lane&31),+1 of head lane>>5
    const float2* xl2 = (const float2*)xl;
    const float2* xr2 = (const float2*)xr;
    const float2* we2 = (const float2*)we;
    const float2* att2 = (const float2*)att;
    const float2* bias2 = (const float2*)bias;
    float2* hout2 = (float2*)hout;
    const float2 w0 = we2[lane], w1 = we2[64 + lane], w2 = we2[128 + lane];
    const float2 av = att2[lane];
    float2 rs = {0, 0}, rq = {0, 0};
    for (int v = gw; v < NN; v += nw) {
      int b = off[v], e1 = off[v + 1];
      float2 xrv = xr2[(size_t)v * 64 + lane];
      float mx = -1e30f, ssum = 0.0f;
      float2 acc = {0, 0};
      int sA = csrc[b];
      float2 row = xl2[(size_t)sA * 64 + lane];
      int sB = (b + 1 < e1) ? csrc[b + 1] : 0;
      for (int j = b; j < e1; j++) {
        float2 cur = row;
        float ea0 = cea[3 * j], ea1 = cea[3 * j + 1], ea2 = cea[3 * j + 2];
        if (j + 1 < e1) row = xl2[(size_t)sB * 64 + lane];
        if (j + 2 < e1) sB = csrc[j + 2];
        float mX = cur.x + xrv.x + ea0 * w0.x + ea1 * w1.x + ea2 * w2.x;
        float mY = cur.y + xrv.y + ea0 * w0.y + ea1 * w1.y + ea2 * w2.y;
        mX = (mX > 0.0f) ? mX : 0.2f * mX;
        mY = (mY > 0.0f) ? mY : 0.2f * mY;
        float l = half_reduce(mX * av.x + mY * av.y);
        float nm = fmaxf(mx, l);
        float sc = __expf(mx - nm);
        float p = __expf(l - nm);
        ssum = ssum * sc + p;
        acc.x = acc.x * sc + p * cur.x;
        acc.y = acc.y * sc + p * cur.y;
        mx = nm;
      }
      float inv = 1.0f / (ssum + 1e-16f);
      float2 myout = {acc.x * inv, acc.y * inv};
      float ox = __shfl_xor(myout.x, 32, 64);
      float oy = __shfl_xor(myout.y, 32, 64);
      if (lane < 32) {
        float2 bv = bias2[lane];
        float2 val = {0.5f * (myout.x + ox) + bv.x, 0.5f * (myout.y + oy) + bv.y};
        hout2[(size_t)v * 32 + lane] = val;
        rs.x += val.x;
        rs.y += val.y;
        rq.x += val.x * val.x;
        rq.y += val.y * val.y;
      }
    }
    if (lane < 32) {
      lsum[wid][2 * lane] = rs.x;
      lsum[wid][2 * lane + 1] = rs.y;
      lsq[wid][2 * lane] = rq.x;
      lsq[wid][2 * lane + 1] = rq.y;
    }
  }
  __syncthreads();
  if (threadIdx.x < C) {
    float a = lsum[0][threadIdx.x] + lsum[1][threadIdx.x] + lsum[2][threadIdx.x] +
              lsum[3][threadIdx.x];
    float q = lsq[0][threadIdx.x] + lsq[1][threadIdx.x] + lsq[2][threadIdx.x] +
              lsq[3][threadIdx.x];
    atomicAdd(&bnsum[threadIdx.x], a);
    atomicAdd(&bnss[threadIdx.x], q);
  }
}

// ---------------- pooling (fused BN2+ELU) + head ----------------
__global__ void k_gcount(const int* __restrict__ batch, int* __restrict__ gcount) {
  int v = blockIdx.x * blockDim.x + threadIdx.x;
  if (v < NN) atomicAdd(&gcount[batch[v]], 1);
}

__global__ void k_goff(const int* __restrict__ gcount, int* __restrict__ goff) {
  __shared__ int s[GG];
  int t = threadIdx.x;
  int x = gcount[t];
  s[t] = x;
  __syncthreads();
#pragma unroll
  for (int o = 1; o < GG; o <<= 1) {
    int v = (t >= o) ? s[t - o] : 0;
    __syncthreads();
    s[t] += v;
    __syncthreads();
  }
  goff[t] = s[t] - x;
}

__global__ void k_pool(const float* __restrict__ h2, const int* __restrict__ goff,
                       const int* __restrict__ gcount, const float* __restrict__ bnsum,
                       const float* __restrict__ bnss, const float* __restrict__ g,
                       const float* __restrict__ be, float* __restrict__ pooled) {
  int gi = blockIdx.x, c = threadIdx.x;  // 64 threads
  float mu = bnsum[c] * (1.0f / NN);
  float var = bnss[c] * (1.0f / NN) - mu * mu;
  float is = rsqrtf(var + BN_EPS) * g[c];
  float sh = be[c] - mu * is;
  int s = goff[gi], n = gcount[gi];
  float acc = 0.0f;
  for (int i = 0; i < n; i++) {
    float y = h2[(size_t)(s + i) * 64 + c] * is + sh;
    y = (y > 0.0f) ? y : (__expf(y) - 1.0f);
    acc += y;
  }
  pooled[gi * 64 + c] = acc / fmaxf((float)n, 1.0f);
}

__global__ void k_fc1(const float* __restrict__ pooled, const float* __restrict__ w,
                      const float* __restrict__ b, float* __restrict__ t1) {
  int i = blockIdx.x * blockDim.x + threadIdx.x;  // 16384
  int g = i >> 5, o = i & 31;
  float acc = b[o];
#pragma unroll 8
  for (int k = 0; k < 64; k++) acc += pooled[g * 64 + k] * w[k * 32 + o];
  t1[i] = acc;
}

__global__ void k_head(const float* __restrict__ t1, const float* __restrict__ g3,
                       const float* __restrict__ be3, const float* __restrict__ fc2w,
                       const float* __restrict__ fc2b, float* __restrict__ out) {
  __shared__ float ssum[32], ssq[32], smu[32], sinv[32];
  int t = threadIdx.x;  // 512 threads, one per graph
  if (t < 32) {
    ssum[t] = 0.0f;
    ssq[t] = 0.0f;
  }
  __syncthreads();
  float y[32];
#pragma unroll
  for (int o = 0; o < 32; o++) y[o] = t1[t * 32 + o];
#pragma unroll
  for (int o = 0; o < 32; o++) {
    atomicAdd(&ssum[o], y[o]);
    atomicAdd(&ssq[o], y[o] * y[o]);
  }
  __syncthreads();
  if (t < 32) {
    float mu = ssum[t] * (1.0f / GG);
    float var = ssq[t] * (1.0f / GG) - mu * mu;
    smu[t] = mu;
    sinv[t] = rsqrtf(var + BN_EPS);
  }
  __syncthreads();
  float acc = fc2b[0];
#pragma unroll
  for (int o = 0; o < 32; o++) {
    float yy = (y[o] - smu[o]) * sinv[o] * g3[o] + be3[o];
    yy = (yy > 0.0f) ? yy : (__expf(yy) - 1.0f);
    acc += yy * fc2w[o];
  }
  out[t] = 1.0f / (1.0f + __expf(-acc));
}

// ---------------- launch ----------------
extern "C" void kernel_launch(void* const* d_in, const int* in_sizes, int n_in,
                              void* d_out, int out_size, void* d_ws, size_t ws_size,
                              hipStream_t stream) {
  const float* x = (const float*)d_in[0];
  const float* ea = (const float*)d_in[1];
  const float* w1l = (const float*)d_in[2];
  const float* b1l = (const float*)d_in[3];
  const float* w1r = (const float*)d_in[4];
  const float* b1r = (const float*)d_in[5];
  const float* w1e = (const float*)d_in[6];
  const float* att1 = (const float*)d_in[7];
  const float* bias1 = (const float*)d_in[8];
  const float* g1 = (const float*)d_in[9];
  const float* be1 = (const float*)d_in[10];
  const float* w2l = (const float*)d_in[11];
  const float* b2l = (const float*)d_in[12];
  const float* w2r = (const float*)d_in[13];
  const float* b2r = (const float*)d_in[14];
  const float* w2e = (const float*)d_in[15];
  const float* att2 = (const float*)d_in[16];
  const float* bias2 = (const float*)d_in[17];
  const float* g2 = (const float*)d_in[18];
  const float* be2 = (const float*)d_in[19];
  const float* fc1w = (const float*)d_in[20];
  const float* fc1b = (const float*)d_in[21];
  const float* g3 = (const float*)d_in[22];
  const float* be3 = (const float*)d_in[23];
  const float* fc2w = (const float*)d_in[24];
  const float* fc2b = (const float*)d_in[25];
  const int* ei = (const int*)d_in[26];
  const int* batch = (const int*)d_in[27];
  float* out = (float*)d_out;

  char* w = (char*)d_ws;
  size_t off = 0;
  auto alloc = [&](size_t bytes) {
    size_t r = off;
    off += (bytes + 255) & ~(size_t)255;
    return r;
  };
  // zero-init region (one memset)
  int* cnt = (int*)(w + alloc(NN * 4));
  int* cur = (int*)(w + alloc(NN * 4));
  int* gcount = (int*)(w + alloc(GG * 4));
  float* bn1sum = (float*)(w + alloc(32 * 4));
  float* bn1ss = (float*)(w + alloc(32 * 4));
  float* bn2sum = (float*)(w + alloc(64 * 4));
  float* bn2ss = (float*)(w + alloc(64 * 4));
  size_t zero_bytes = off;
  // rest
  int* csr_off = (int*)(w + alloc((size_t)(NN + 1) * 4));
  int* bsum = (int*)(w + alloc(512 * 4));
  int* goff = (int*)(w + alloc((size_t)(GG + 1) * 4));
  int* csrc = (int*)(w + alloc((size_t)ET * 4));
  float* cea = (float*)(w + alloc((size_t)ET * 12));
  float* xl = (float*)(w + alloc((size_t)NN * 128 * 4));
  float* xr = (float*)(w + alloc((size_t)NN * 128 * 4));
  float* h1 = (float*)(w + alloc((size_t)NN * 32 * 4));
  float* h2 = (float*)(w + alloc((size_t)NN * 64 * 4));
  float* pooled = (float*)(w + alloc((size_t)GG * 64 * 4));
  float* t1 = (float*)(w + alloc((size_t)GG * 32 * 4));
  (void)ws_size;
  (void)in_sizes;
  (void)n_in;
  (void)out_size;

  hipMemsetAsync(d_ws, 0, zero_bytes, stream);

  // CSR build
  k_hist<<<EE / 256, 256, 0, stream>>>(ei, cnt);
  k_scan_a<<<512, 256, 0, stream>>>(cnt, csr_off, bsum);
  k_scan_b<<<1, 512, 0, stream>>>(bsum);
  k_scan_c<<<512, 256, 0, stream>>>(csr_off, bsum);
  k_scatter<<<EE / 256, 256, 0, stream>>>(ei, ea, csr_off, cur, csrc, cea);
  k_selfloop<<<NN / 256, 256, 0, stream>>>(csr_off, csrc, cea);

  // layer 1 (HC=64, C=32)
  k_lin<64, 64, false><<<2048, 256, 0, stream>>>(x, w1l, b1l, w1r, b1r, xl, xr,
                                                 nullptr, nullptr, nullptr, nullptr);
  k_gat<64><<<2048, 256, 0, stream>>>(csr_off, csrc, cea, xl, xr, w1e, att1, bias1,
                                      h1, bn1sum, bn1ss);

  // layer 2 (HC=128, C=64) — BN1+ELU fused into the staging load
  k_lin<32, 128, true><<<2048, 256, 0, stream>>>(h1, w2l, b2l, w2r, b2r, xl, xr,
                                                 bn1sum, bn1ss, g1, be1);
  k_gat<128><<<2048, 256, 0, stream>>>(csr_off, csrc, cea, xl, xr, w2e, att2, bias2,
                                       h2, bn2sum, bn2ss);

  // pooling (BN2+ELU fused) + head
  k_gcount<<<NN / 256, 256, 0, stream>>>(batch, gcount);
  k_goff<<<1, GG, 0, stream>>>(gcount, goff);
  k_pool<<<GG, 64, 0, stream>>>(h2, goff, gcount, bn2sum, bn2ss, g2, be2, pooled);
  k_fc1<<<64, 256, 0, stream>>>(pooled, fc1w, fc1b, t1);
  k_head<<<1, GG, 0, stream>>>(t1, g3, be3, fc2w, fc2b, out);
}

// Round 3
// 1358.923 us; speedup vs baseline: 1.5883x; 1.0234x over previous
//
#include <hip/hip_runtime.h>
#include <math.h>

#define NN 131072
#define EE 2097152
#define ET (EE + NN)
#define GG 512
#define BN_EPS 1e-5f

// ---------------- CSR build ----------------
__global__ void k_hist(const int* __restrict__ ei, int* __restrict__ cnt) {
  int e = blockIdx.x * blockDim.x + threadIdx.x;
  if (e < EE) atomicAdd(&cnt[ei[EE + e]], 1);
}

__global__ void k_scan_a(const int* __restrict__ cnt, int* __restrict__ off_out,
                         int* __restrict__ bsum) {
  __shared__ int s[256];
  int i = blockIdx.x * 256 + threadIdx.x;
  int x = cnt[i] + 1;  // +1 self loop
  s[threadIdx.x] = x;
  __syncthreads();
#pragma unroll
  for (int o = 1; o < 256; o <<= 1) {
    int t = (threadIdx.x >= o) ? s[threadIdx.x - o] : 0;
    __syncthreads();
    s[threadIdx.x] += t;
    __syncthreads();
  }
  off_out[i] = s[threadIdx.x] - x;  // exclusive within block
  if (threadIdx.x == 255) bsum[blockIdx.x] = s[255];
}

__global__ void k_scan_b(int* __restrict__ bsum) {
  __shared__ int s[512];
  int t = threadIdx.x;
  int x = bsum[t];
  s[t] = x;
  __syncthreads();
#pragma unroll
  for (int o = 1; o < 512; o <<= 1) {
    int v = (t >= o) ? s[t - o] : 0;
    __syncthreads();
    s[t] += v;
    __syncthreads();
  }
  bsum[t] = s[t] - x;  // exclusive, in place
}

__global__ void k_scan_c(int* __restrict__ off_out, const int* __restrict__ bsum) {
  int i = blockIdx.x * 256 + threadIdx.x;
  off_out[i] += bsum[blockIdx.x];
  if (i == 0) off_out[NN] = ET;
}

__global__ void k_scatter(const int* __restrict__ ei, const float* __restrict__ ea,
                          const int* __restrict__ off, int* __restrict__ cur,
                          int* __restrict__ csrc, float4* __restrict__ cea) {
  int e = blockIdx.x * blockDim.x + threadIdx.x;
  if (e >= EE) return;
  int s = ei[e], d = ei[EE + e];
  int p = off[d] + atomicAdd(&cur[d], 1);
  csrc[p] = s;
  float4 t = {ea[3 * e], ea[3 * e + 1], ea[3 * e + 2], 0.0f};
  cea[p] = t;
}

// self-loop slot = last slot of each node; attr = mean of incoming real-edge attrs
__global__ void k_selfloop(const int* __restrict__ off, int* __restrict__ csrc,
                           float4* __restrict__ cea) {
  int v = blockIdx.x * blockDim.x + threadIdx.x;
  if (v >= NN) return;
  int b = off[v];
  int d = off[v + 1] - b - 1;  // real in-degree
  float s0 = 0.f, s1 = 0.f, s2 = 0.f;
  for (int j = b; j < b + d; j++) {
    float4 t = cea[j];
    s0 += t.x;
    s1 += t.y;
    s2 += t.z;
  }
  float inv = 1.0f / (float)(d > 0 ? d : 1);
  int sl = b + d;
  csrc[sl] = v;
  float4 t = {s0 * inv, s1 * inv, s2 * inv, 0.0f};
  cea[sl] = t;
}

// ---------------- node linear: xl = f(x)@wl+bl ; xr = f(x)@wr+br ----------------
// DO_BN: f = elu(bn(x)) using stats in bnsum/bnss (K must == C of previous layer)
template <int K, int O, bool DO_BN>
__global__ void k_lin(const float* __restrict__ x, const float* __restrict__ wl,
                      const float* __restrict__ bl, const float* __restrict__ wr,
                      const float* __restrict__ br, float* __restrict__ xl,
                      float* __restrict__ xr, const float* __restrict__ bnsum,
                      const float* __restrict__ bnss, const float* __restrict__ g,
                      const float* __restrict__ be) {
  constexpr int NPB = 256 / O;  // nodes per block-iteration
  __shared__ float swl[K * O], swr[K * O], sx[NPB * K];
  __shared__ float sscale[K], sshift[K];
  for (int i = threadIdx.x; i < K * O; i += 256) {
    swl[i] = wl[i];
    swr[i] = wr[i];
  }
  if (DO_BN && threadIdx.x < K) {
    int c = threadIdx.x;
    float mu = bnsum[c] * (1.0f / NN);
    float var = bnss[c] * (1.0f / NN) - mu * mu;
    float is = rsqrtf(var + BN_EPS) * g[c];
    sscale[c] = is;
    sshift[c] = be[c] - mu * is;
  }
  int o = threadIdx.x % O;
  int ln = threadIdx.x / O;
  float blv = bl[o], brv = br[o];
  __syncthreads();
  for (int v0 = blockIdx.x * NPB; v0 < NN; v0 += gridDim.x * NPB) {
    __syncthreads();
    for (int i = threadIdx.x; i < NPB * K; i += 256) {
      float xv = x[(size_t)v0 * K + i];
      if (DO_BN) {
        int c = i & (K - 1);
        xv = xv * sscale[c] + sshift[c];
        xv = (xv > 0.0f) ? xv : (__expf(xv) - 1.0f);
      }
      sx[i] = xv;
    }
    __syncthreads();
    float al = blv, ar = brv;
#pragma unroll 8
    for (int k = 0; k < K; k++) {
      float xv = sx[ln * K + k];
      al += xv * swl[k * O + o];
      ar += xv * swr[k * O + o];
    }
    int v = v0 + ln;
    xl[(size_t)v * O + o] = al;
    xr[(size_t)v * O + o] = ar;
  }
}

// ---------------- fused GATv2 edge phase ----------------
// One wave per node; 32 "channel lanes" (lane&31) cover all HC channels with
// vector loads; the two lane-halves process even/odd CSR slots (2 edges/iter).
// No running max: logits are bounded (~±5), exp() is safe in fp32 and
// p/sum(p) == softmax exactly up to rounding.
// 16-lane group reduce (head h of stream s): masks 1,2,4,8.

// HC=128: float4/lane. head0 = lanes 0..15 (ch 4l..4l+3), head1 = lanes 16..31.
__global__ void k_gat128(const int* __restrict__ off, const int* __restrict__ csrc,
                         const float4* __restrict__ cea, const float4* __restrict__ xl,
                         const float4* __restrict__ xr, const float4* __restrict__ we,
                         const float4* __restrict__ att, const float4* __restrict__ bias,
                         float4* __restrict__ hout, float* __restrict__ bnsum,
                         float* __restrict__ bnss) {
  __shared__ float lsum[4][64], lsq[4][64];
  int lane = threadIdx.x & 63;
  int wid = threadIdx.x >> 6;
  int cl = lane & 31;    // channel lane
  int half = lane >> 5;  // edge stream (even/odd slots)
  const float4 w0 = we[cl], w1 = we[32 + cl], w2 = we[64 + cl];
  const float4 av = att[cl];
  float4 rs = {0, 0, 0, 0}, rq = {0, 0, 0, 0};
  for (int v = blockIdx.x * 4 + wid; v < NN; v += gridDim.x * 4) {
    int b = off[v], e1 = off[v + 1];
    float4 xrv = xr[(size_t)v * 32 + cl];
    float ssum = 0.0f;
    float4 acc = {0, 0, 0, 0};
    // software pipeline (2-stage): indices 2 iters ahead, rows 1 iter ahead
    int j0 = min(b + half, e1 - 1);
    int s0 = csrc[j0];
    float4 eaNext = cea[j0];
    float4 rowNext = xl[(size_t)s0 * 32 + cl];
    int j1 = min(b + 2 + half, e1 - 1);
    int sNN = csrc[j1];
    float4 eaNN = cea[j1];
    for (int j = b; j < e1; j += 2) {
      float4 cur = rowNext;
      float4 ea = eaNext;
      bool valid = (j + half) < e1;
      int sN = sNN;
      eaNext = eaNN;
      int jn = min(j + 4 + half, e1 - 1);
      sNN = csrc[jn];
      eaNN = cea[jn];
      rowNext = xl[(size_t)sN * 32 + cl];
      float mx = cur.x + xrv.x + ea.x * w0.x + ea.y * w1.x + ea.z * w2.x;
      float my = cur.y + xrv.y + ea.x * w0.y + ea.y * w1.y + ea.z * w2.y;
      float mz = cur.z + xrv.z + ea.x * w0.z + ea.y * w1.z + ea.z * w2.z;
      float mw = cur.w + xrv.w + ea.x * w0.w + ea.y * w1.w + ea.z * w2.w;
      mx = fmaxf(mx, 0.2f * mx);  // leaky_relu (slope<1)
      my = fmaxf(my, 0.2f * my);
      mz = fmaxf(mz, 0.2f * mz);
      mw = fmaxf(mw, 0.2f * mw);
      float l = mx * av.x + my * av.y + mz * av.z + mw * av.w;
      l += __shfl_xor(l, 1, 64);
      l += __shfl_xor(l, 2, 64);
      l += __shfl_xor(l, 4, 64);
      l += __shfl_xor(l, 8, 64);
      float p = valid ? __expf(l) : 0.0f;
      ssum += p;
      acc.x += p * cur.x;
      acc.y += p * cur.y;
      acc.z += p * cur.z;
      acc.w += p * cur.w;
    }
    // combine even/odd streams
    ssum += __shfl_xor(ssum, 32, 64);
    acc.x += __shfl_xor(acc.x, 32, 64);
    acc.y += __shfl_xor(acc.y, 32, 64);
    acc.z += __shfl_xor(acc.z, 32, 64);
    acc.w += __shfl_xor(acc.w, 32, 64);
    float inv = 1.0f / (ssum + 1e-16f);
    float4 o = {acc.x * inv, acc.y * inv, acc.z * inv, acc.w * inv};
    // head mean: partner lane ^16 holds same head-channel of other head
    float px = __shfl_xor(o.x, 16, 64);
    float py = __shfl_xor(o.y, 16, 64);
    float pz = __shfl_xor(o.z, 16, 64);
    float pw = __shfl_xor(o.w, 16, 64);
    if (lane < 16) {
      float4 bv = bias[lane];
      float4 val = {0.5f * (o.x + px) + bv.x, 0.5f * (o.y + py) + bv.y,
                    0.5f * (o.z + pz) + bv.z, 0.5f * (o.w + pw) + bv.w};
      hout[(size_t)v * 16 + lane] = val;
      rs.x += val.x; rs.y += val.y; rs.z += val.z; rs.w += val.w;
      rq.x += val.x * val.x; rq.y += val.y * val.y;
      rq.z += val.z * val.z; rq.w += val.w * val.w;
    }
  }
  if (lane < 16) {
    lsum[wid][4 * lane] = rs.x;
    lsum[wid][4 * lane + 1] = rs.y;
    lsum[wid][4 * lane + 2] = rs.z;
    lsum[wid][4 * lane + 3] = rs.w;
    lsq[wid][4 * lane] = rq.x;
    lsq[wid][4 * lane + 1] = rq.y;
    lsq[wid][4 * lane + 2] = rq.z;
    lsq[wid][4 * lane + 3] = rq.w;
  }
  __syncthreads();
  if (threadIdx.x < 64) {
    float a = lsum[0][threadIdx.x] + lsum[1][threadIdx.x] + lsum[2][threadIdx.x] +
              lsum[3][threadIdx.x];
    float q = lsq[0][threadIdx.x] + lsq[1][threadIdx.x] + lsq[2][threadIdx.x] +
              lsq[3][threadIdx.x];
    atomicAdd(&bnsum[threadIdx.x], a);
    atomicAdd(&bnss[threadIdx.x], q);
  }
}

// HC=64: float2/lane. head0 = lanes 0..15 (ch 2l..2l+1), head1 = lanes 16..31.
__global__ void k_gat64(const int* __restrict__ off, const int* __restrict__ csrc,
                        const float4* __restrict__ cea, const float2* __restrict__ xl,
                        const float2* __restrict__ xr, const float2* __restrict__ we,
                        const float2* __restrict__ att, const float2* __restrict__ bias,
                        float2* __restrict__ hout, float* __restrict__ bnsum,
                        float* __restrict__ bnss) {
  __shared__ float lsum[4][32], lsq[4][32];
  int lane = threadIdx.x & 63;
  int wid = threadIdx.x >> 6;
  int cl = lane & 31;
  int half = lane >> 5;
  const float2 w0 = we[cl], w1 = we[32 + cl], w2 = we[64 + cl];
  const float2 av = att[cl];
  float2 rs = {0, 0}, rq = {0, 0};
  for (int v = blockIdx.x * 4 + wid; v < NN; v += gridDim.x * 4) {
    int b = off[v], e1 = off[v + 1];
    float2 xrv = xr[(size_t)v * 32 + cl];
    float ssum = 0.0f;
    float2 acc = {0, 0};
    int j0 = min(b + half, e1 - 1);
    int s0 = csrc[j0];
    float4 eaNext = cea[j0];
    float2 rowNext = xl[(size_t)s0 * 32 + cl];
    int j1 = min(b + 2 + half, e1 - 1);
    int sNN = csrc[j1];
    float4 eaNN = cea[j1];
    for (int j = b; j < e1; j += 2) {
      float2 cur = rowNext;
      float4 ea = eaNext;
      bool valid = (j + half) < e1;
      int sN = sNN;
      eaNext = eaNN;
      int jn = min(j + 4 + half, e1 - 1);
      sNN = csrc[jn];
      eaNN = cea[jn];
      rowNext = xl[(size_t)sN * 32 + cl];
      float mx = cur.x + xrv.x + ea.x * w0.x + ea.y * w1.x + ea.z * w2.x;
      float my = cur.y + xrv.y + ea.x * w0.y + ea.y * w1.y + ea.z * w2.y;
      mx = fmaxf(mx, 0.2f * mx);
      my = fmaxf(my, 0.2f * my);
      float l = mx * av.x + my * av.y;
      l += __shfl_xor(l, 1, 64);
      l += __shfl_xor(l, 2, 64);
      l += __shfl_xor(l, 4, 64);
      l += __shfl_xor(l, 8, 64);
      float p = valid ? __expf(l) : 0.0f;
      ssum += p;
      acc.x += p * cur.x;
      acc.y += p * cur.y;
    }
    ssum += __shfl_xor(ssum, 32, 64);
    acc.x += __shfl_xor(acc.x, 32, 64);
    acc.y += __shfl_xor(acc.y, 32, 64);
    float inv = 1.0f / (ssum + 1e-16f);
    float2 o = {acc.x * inv, acc.y * inv};
    float px = __shfl_xor(o.x, 16, 64);
    float py = __shfl_xor(o.y, 16, 64);
    if (lane < 16) {
      float2 bv = bias[lane];
      float2 val = {0.5f * (o.x + px) + bv.x, 0.5f * (o.y + py) + bv.y};
      hout[(size_t)v * 16 + lane] = val;
      rs.x += val.x; rs.y += val.y;
      rq.x += val.x * val.x; rq.y += val.y * val.y;
    }
  }
  if (lane < 16) {
    lsum[wid][2 * lane] = rs.x;
    lsum[wid][2 * lane + 1] = rs.y;
    lsq[wid][2 * lane] = rq.x;
    lsq[wid][2 * lane + 1] = rq.y;
  }
  __syncthreads();
  if (threadIdx.x < 32) {
    float a = lsum[0][threadIdx.x] + lsum[1][threadIdx.x] + lsum[2][threadIdx.x] +
              lsum[3][threadIdx.x];
    float q = lsq[0][threadIdx.x] + lsq[1][threadIdx.x] + lsq[2][threadIdx.x] +
              lsq[3][threadIdx.x];
    atomicAdd(&bnsum[threadIdx.x], a);
    atomicAdd(&bnss[threadIdx.x], q);
  }
}

// ---------------- pooling (fused BN2+ELU) + head ----------------
__global__ void k_gcount(const int* __restrict__ batch, int* __restrict__ gcount) {
  int v = blockIdx.x * blockDim.x + threadIdx.x;
  if (v < NN) atomicAdd(&gcount[batch[v]], 1);
}

__global__ void k_goff(const int* __restrict__ gcount, int* __restrict__ goff) {
  __shared__ int s[GG];
  int t = threadIdx.x;
  int x = gcount[t];
  s[t] = x;
  __syncthreads();
#pragma unroll
  for (int o = 1; o < GG; o <<= 1) {
    int v = (t >= o) ? s[t - o] : 0;
    __syncthreads();
    s[t] += v;
    __syncthreads();
  }
  goff[t] = s[t] - x;
}

__global__ void k_pool(const float* __restrict__ h2, const int* __restrict__ goff,
                       const int* __restrict__ gcount, const float* __restrict__ bnsum,
                       const float* __restrict__ bnss, const float* __restrict__ g,
                       const float* __restrict__ be, float* __restrict__ pooled) {
  int gi = blockIdx.x, c = threadIdx.x;  // 64 threads
  float mu = bnsum[c] * (1.0f / NN);
  float var = bnss[c] * (1.0f / NN) - mu * mu;
  float is = rsqrtf(var + BN_EPS) * g[c];
  float sh = be[c] - mu * is;
  int s = goff[gi], n = gcount[gi];
  float acc = 0.0f;
  for (int i = 0; i < n; i++) {
    float y = h2[(size_t)(s + i) * 64 + c] * is + sh;
    y = (y > 0.0f) ? y : (__expf(y) - 1.0f);
    acc += y;
  }
  pooled[gi * 64 + c] = acc / fmaxf((float)n, 1.0f);
}

__global__ void k_fc1(const float* __restrict__ pooled, const float* __restrict__ w,
                      const float* __restrict__ b, float* __restrict__ t1) {
  int i = blockIdx.x * blockDim.x + threadIdx.x;  // 16384
  int g = i >> 5, o = i & 31;
  float acc = b[o];
#pragma unroll 8
  for (int k = 0; k < 64; k++) acc += pooled[g * 64 + k] * w[k * 32 + o];
  t1[i] = acc;
}

__global__ void k_head(const float* __restrict__ t1, const float* __restrict__ g3,
                       const float* __restrict__ be3, const float* __restrict__ fc2w,
                       const float* __restrict__ fc2b, float* __restrict__ out) {
  __shared__ float ssum[32], ssq[32], smu[32], sinv[32];
  int t = threadIdx.x;  // 512 threads, one per graph
  if (t < 32) {
    ssum[t] = 0.0f;
    ssq[t] = 0.0f;
  }
  __syncthreads();
  float y[32];
#pragma unroll
  for (int o = 0; o < 32; o++) y[o] = t1[t * 32 + o];
#pragma unroll
  for (int o = 0; o < 32; o++) {
    atomicAdd(&ssum[o], y[o]);
    atomicAdd(&ssq[o], y[o] * y[o]);
  }
  __syncthreads();
  if (t < 32) {
    float mu = ssum[t] * (1.0f / GG);
    float var = ssq[t] * (1.0f / GG) - mu * mu;
    smu[t] = mu;
    sinv[t] = rsqrtf(var + BN_EPS);
  }
  __syncthreads();
  float acc = fc2b[0];
#pragma unroll
  for (int o = 0; o < 32; o++) {
    float yy = (y[o] - smu[o]) * sinv[o] * g3[o] + be3[o];
    yy = (yy > 0.0f) ? yy : (__expf(yy) - 1.0f);
    acc += yy * fc2w[o];
  }
  out[t] = 1.0f / (1.0f + __expf(-acc));
}

// ---------------- launch ----------------
extern "C" void kernel_launch(void* const* d_in, const int* in_sizes, int n_in,
                              void* d_out, int out_size, void* d_ws, size_t ws_size,
                              hipStream_t stream) {
  const float* x = (const float*)d_in[0];
  const float* ea = (const float*)d_in[1];
  const float* w1l = (const float*)d_in[2];
  const float* b1l = (const float*)d_in[3];
  const float* w1r = (const float*)d_in[4];
  const float* b1r = (const float*)d_in[5];
  const float* w1e = (const float*)d_in[6];
  const float* att1 = (const float*)d_in[7];
  const float* bias1 = (const float*)d_in[8];
  const float* g1 = (const float*)d_in[9];
  const float* be1 = (const float*)d_in[10];
  const float* w2l = (const float*)d_in[11];
  const float* b2l = (const float*)d_in[12];
  const float* w2r = (const float*)d_in[13];
  const float* b2r = (const float*)d_in[14];
  const float* w2e = (const float*)d_in[15];
  const float* att2 = (const float*)d_in[16];
  const float* bias2 = (const float*)d_in[17];
  const float* g2 = (const float*)d_in[18];
  const float* be2 = (const float*)d_in[19];
  const float* fc1w = (const float*)d_in[20];
  const float* fc1b = (const float*)d_in[21];
  const float* g3 = (const float*)d_in[22];
  const float* be3 = (const float*)d_in[23];
  const float* fc2w = (const float*)d_in[24];
  const float* fc2b = (const float*)d_in[25];
  const int* ei = (const int*)d_in[26];
  const int* batch = (const int*)d_in[27];
  float* out = (float*)d_out;

  char* w = (char*)d_ws;
  size_t off = 0;
  auto alloc = [&](size_t bytes) {
    size_t r = off;
    off += (bytes + 255) & ~(size_t)255;
    return r;
  };
  // zero-init region (one memset)
  int* cnt = (int*)(w + alloc(NN * 4));
  int* cur = (int*)(w + alloc(NN * 4));
  int* gcount = (int*)(w + alloc(GG * 4));
  float* bn1sum = (float*)(w + alloc(32 * 4));
  float* bn1ss = (float*)(w + alloc(32 * 4));
  float* bn2sum = (float*)(w + alloc(64 * 4));
  float* bn2ss = (float*)(w + alloc(64 * 4));
  size_t zero_bytes = off;
  // rest
  int* csr_off = (int*)(w + alloc((size_t)(NN + 1) * 4));
  int* bsum = (int*)(w + alloc(512 * 4));
  int* goff = (int*)(w + alloc((size_t)(GG + 1) * 4));
  int* csrc = (int*)(w + alloc((size_t)ET * 4));
  float4* cea = (float4*)(w + alloc((size_t)ET * 16));
  float* xl = (float*)(w + alloc((size_t)NN * 128 * 4));
  float* xr = (float*)(w + alloc((size_t)NN * 128 * 4));
  float* h1 = (float*)(w + alloc((size_t)NN * 32 * 4));
  float* h2 = (float*)(w + alloc((size_t)NN * 64 * 4));
  float* pooled = (float*)(w + alloc((size_t)GG * 64 * 4));
  float* t1 = (float*)(w + alloc((size_t)GG * 32 * 4));
  (void)ws_size;
  (void)in_sizes;
  (void)n_in;
  (void)out_size;

  hipMemsetAsync(d_ws, 0, zero_bytes, stream);

  // CSR build
  k_hist<<<EE / 256, 256, 0, stream>>>(ei, cnt);
  k_scan_a<<<512, 256, 0, stream>>>(cnt, csr_off, bsum);
  k_scan_b<<<1, 512, 0, stream>>>(bsum);
  k_scan_c<<<512, 256, 0, stream>>>(csr_off, bsum);
  k_scatter<<<EE / 256, 256, 0, stream>>>(ei, ea, csr_off, cur, csrc, cea);
  k_selfloop<<<NN / 256, 256, 0, stream>>>(csr_off, csrc, cea);

  // layer 1 (HC=64, C=32)
  k_lin<64, 64, false><<<2048, 256, 0, stream>>>(x, w1l, b1l, w1r, b1r, xl, xr,
                                                 nullptr, nullptr, nullptr, nullptr);
  k_gat64<<<2048, 256, 0, stream>>>(csr_off, csrc, cea, (const float2*)xl,
                                    (const float2*)xr, (const float2*)w1e,
                                    (const float2*)att1, (const float2*)bias1,
                                    (float2*)h1, bn1sum, bn1ss);

  // layer 2 (HC=128, C=64) — BN1+ELU fused into the staging load
  k_lin<32, 128, true><<<2048, 256, 0, stream>>>(h1, w2l, b2l, w2r, b2r, xl, xr,
                                                 bn1sum, bn1ss, g1, be1);
  k_gat128<<<2048, 256, 0, stream>>>(csr_off, csrc, cea, (const float4*)xl,
                                     (const float4*)xr, (const float4*)w2e,
                                     (const float4*)att2, (const float4*)bias2,
                                     (float4*)h2, bn2sum, bn2ss);

  // pooling (BN2+ELU fused) + head
  k_gcount<<<NN / 256, 256, 0, stream>>>(batch, gcount);
  k_goff<<<1, GG, 0, stream>>>(gcount, goff);
  k_pool<<<GG, 64, 0, stream>>>(h2, goff, gcount, bn2sum, bn2ss, g2, be2, pooled);
  k_fc1<<<64, 256, 0, stream>>>(pooled, fc1w, fc1b, t1);
  k_head<<<1, GG, 0, stream>>>(t1, g3, be3, fc2w, fc2b, out);
}